// Round 1
// baseline (141.938 us; speedup 1.0000x reference)
//
#include <hip/hip_runtime.h>
#include <math.h>

#define T_TOK   131072
#define NCODE   512
#define DDIM    64
#define BT      128      // tokens per block

// output layout (float32, concatenated in return order)
#define OFF_LOSS 0
#define OFF_Q    1                    // 8388608 elements
#define OFF_PERP 8388609
#define OFF_CB   8388610              // 32768 elements
#define OFF_IDX  8421378              // 131072 elements

// ws layout (bytes): [0] float loss_acc ; [64] int counts[512] ; [4096] float invn[512]

__global__ __launch_bounds__(512) void prep_kernel(const float* __restrict__ cb,
                                                   float* __restrict__ out,
                                                   float* __restrict__ invn,
                                                   int* __restrict__ counts_g,
                                                   float* __restrict__ loss_g)
{
    int r = threadIdx.x;  // 0..511, one code row per thread
    float s = 0.f;
    #pragma unroll
    for (int i = 0; i < 64; ++i) { float v = cb[r * 64 + i]; s = fmaf(v, v, s); }
    invn[r] = 1.0f / fmaxf(sqrtf(s), 1e-12f);
    counts_g[r] = 0;
    if (r == 0) loss_g[0] = 0.f;
    // passthrough copy of raw codebook (coalesced)
    for (int g = r; g < NCODE * 64; g += 512) out[OFF_CB + g] = cb[g];
}

__global__ __launch_bounds__(256) void main_kernel(const float* __restrict__ x,
                                                   const float* __restrict__ cbraw,
                                                   const float* __restrict__ invn_g,
                                                   int* __restrict__ counts_g,
                                                   float* __restrict__ loss_g,
                                                   float* __restrict__ out)
{
    __shared__ float xs[64 * 132];      // x transposed [d][token], pad 132
    __shared__ float cs[64 * 132];      // code chunk transposed [d][code], pad 132
    __shared__ float inv_nx[BT];
    __shared__ int   idxs[BT];
    __shared__ int   counts_lds[NCODE];
    __shared__ float loss_lds;

    const int tid = threadIdx.x;
    const int tx = tid & 15;            // code group
    const int ty = tid >> 4;            // token group (8 tokens each)
    const int tok0 = blockIdx.x * BT;

    // ---- stage x tile (coalesced float4), transpose into LDS ----
    const float4* xg4 = (const float4*)x + (size_t)tok0 * 16;
    #pragma unroll
    for (int i = 0; i < 8; ++i) {
        int f4 = tid + i * 256;         // 0..2047
        float4 v = xg4[f4];
        int t  = f4 >> 4;               // token 0..127
        int d4 = (f4 & 15) << 2;        // d 0..60
        xs[(d4 + 0) * 132 + t] = v.x;
        xs[(d4 + 1) * 132 + t] = v.y;
        xs[(d4 + 2) * 132 + t] = v.z;
        xs[(d4 + 3) * 132 + t] = v.w;
    }
    counts_lds[tid] = 0;
    counts_lds[tid + 256] = 0;
    if (tid == 0) loss_lds = 0.f;
    __syncthreads();

    // per-token inverse norms (only needed for the loss term)
    if (tid < BT) {
        float s = 0.f;
        #pragma unroll
        for (int d = 0; d < 64; ++d) { float v = xs[d * 132 + tid]; s = fmaf(v, v, s); }
        inv_nx[tid] = 1.0f / fmaxf(sqrtf(s), 1e-12f);
    }

    float bm[8]; int bi[8];
    #pragma unroll
    for (int i = 0; i < 8; ++i) { bm[i] = -1e30f; bi[i] = 0; }

    const float4* cg4 = (const float4*)cbraw;

    for (int c0 = 0; c0 < NCODE; c0 += 128) {
        // ---- stage 128 normalized codes, transposed ----
        #pragma unroll
        for (int i = 0; i < 8; ++i) {
            int f4 = tid + i * 256;
            int n  = f4 >> 4;           // local code 0..127
            int d4 = (f4 & 15) << 2;
            int g  = c0 + n;
            float4 v = cg4[g * 16 + (f4 & 15)];
            float s = invn_g[g];
            cs[(d4 + 0) * 132 + n] = v.x * s;
            cs[(d4 + 1) * 132 + n] = v.y * s;
            cs[(d4 + 2) * 132 + n] = v.z * s;
            cs[(d4 + 3) * 132 + n] = v.w * s;
        }
        __syncthreads();

        float acc[8][8];
        #pragma unroll
        for (int i = 0; i < 8; ++i)
            #pragma unroll
            for (int j = 0; j < 8; ++j) acc[i][j] = 0.f;

        #pragma unroll 4
        for (int d = 0; d < 64; ++d) {
            const float* xrow = xs + d * 132 + ty * 8;
            const float* crow = cs + d * 132;
            float4 x0 = *(const float4*)(xrow);
            float4 x1 = *(const float4*)(xrow + 4);
            float4 ca = *(const float4*)(crow + 4 * tx);
            float4 cbv = *(const float4*)(crow + 64 + 4 * tx);
            float xv[8] = {x0.x, x0.y, x0.z, x0.w, x1.x, x1.y, x1.z, x1.w};
            float cv[8] = {ca.x, ca.y, ca.z, ca.w, cbv.x, cbv.y, cbv.z, cbv.w};
            #pragma unroll
            for (int i = 0; i < 8; ++i)
                #pragma unroll
                for (int j = 0; j < 8; ++j)
                    acc[i][j] = fmaf(xv[i], cv[j], acc[i][j]);
        }

        // running argmax, ascending code order, strict > keeps first max
        #pragma unroll
        for (int j = 0; j < 8; ++j) {
            int code = c0 + ((j < 4) ? (4 * tx + j) : (64 + 4 * tx + (j - 4)));
            #pragma unroll
            for (int i = 0; i < 8; ++i) {
                if (acc[i][j] > bm[i]) { bm[i] = acc[i][j]; bi[i] = code; }
            }
        }
        __syncthreads();
    }

    // ---- cross-thread (tx) argmax reduction within 16-lane groups ----
    float lossp = 0.f;
    #pragma unroll
    for (int i = 0; i < 8; ++i) {
        float v = bm[i]; int ci = bi[i];
        for (int off = 8; off > 0; off >>= 1) {
            float v2 = __shfl_xor(v, off, 16);
            int   c2 = __shfl_xor(ci, off, 16);
            if (v2 > v || (v2 == v && c2 < ci)) { v = v2; ci = c2; }
        }
        if (tx == 0) {
            int t = ty * 8 + i;
            idxs[t] = ci;
            lossp += 2.f - 2.f * v * inv_nx[t];   // ||q-x̂||² = 2 - 2 cos
            atomicAdd(&counts_lds[ci], 1);
        }
    }
    if (tx == 0) atomicAdd(&loss_lds, lossp);
    __syncthreads();

    // indices (as float, exact)
    if (tid < BT) out[OFF_IDX + tok0 + tid] = (float)idxs[tid];

    // quantized_st = normalized codebook gather (coalesced dword stores; OFF_Q is odd)
    for (int e = tid; e < BT * 64; e += 256) {
        int t = e >> 6;
        int d = e & 63;
        int n = idxs[t];
        out[OFF_Q + (size_t)(tok0 + t) * 64 + d] = cbraw[n * 64 + d] * invn_g[n];
    }

    // flush histogram + loss partial
    int ca = counts_lds[tid];
    int cb2 = counts_lds[tid + 256];
    if (ca)  atomicAdd(&counts_g[tid], ca);
    if (cb2) atomicAdd(&counts_g[tid + 256], cb2);
    if (tid == 0) atomicAdd(loss_g, loss_lds);
}

__global__ __launch_bounds__(512) void fin_kernel(const int* __restrict__ counts_g,
                                                  const float* __restrict__ loss_g,
                                                  float* __restrict__ out)
{
    __shared__ double red[512];
    int t = threadIdx.x;
    float p = (float)counts_g[t] * (1.0f / (float)T_TOK);
    red[t] = (double)(p * logf(p + 1e-10f));
    __syncthreads();
    for (int s = 256; s > 0; s >>= 1) {
        if (t < s) red[t] += red[t + s];
        __syncthreads();
    }
    if (t == 0) {
        out[OFF_PERP] = expf(-(float)red[0]);
        out[OFF_LOSS] = loss_g[0] * (1.25f / ((float)T_TOK * 64.f));
    }
}

extern "C" void kernel_launch(void* const* d_in, const int* in_sizes, int n_in,
                              void* d_out, int out_size, void* d_ws, size_t ws_size,
                              hipStream_t stream)
{
    const float* x  = (const float*)d_in[0];   // encoded_patch_input [128,8,128,64]
    const float* cb = (const float*)d_in[1];   // codebook_weight [512,64]
    float* out = (float*)d_out;
    char*  ws  = (char*)d_ws;
    float* loss_g   = (float*)(ws + 0);
    int*   counts_g = (int*)(ws + 64);
    float* invn     = (float*)(ws + 4096);

    prep_kernel<<<1, 512, 0, stream>>>(cb, out, invn, counts_g, loss_g);
    main_kernel<<<T_TOK / BT, 256, 0, stream>>>(x, cb, invn, counts_g, loss_g, out);
    fin_kernel<<<1, 512, 0, stream>>>(counts_g, loss_g, out);
}

// Round 2
// 110.679 us; speedup vs baseline: 1.2824x; 1.2824x over previous
//
#include <hip/hip_runtime.h>
#include <math.h>

#define T_TOK 131072
#define NCODE 512
#define BT    128

// output layout (float32, concatenated in return order)
#define OFF_LOSS 0
#define OFF_Q    1                    // 8388608 elements
#define OFF_PERP 8388609
#define OFF_CB   8388610              // 32768 elements
#define OFF_IDX  8421378              // 131072 elements

// ws layout (bytes):
//   0      : float loss_acc
//   64     : int counts[512]
//   4096   : float cbn[512*64]           normalized codebook fp32
//   135168 : uint4 aplane[8 chunks][3 splits][8 kb][66]  split bf16 codebook
#define CBN_OFF    4096
#define APLANE_OFF 135168
#define CHUNK_U4   1584               // 3*8*66 uint4 per 64-code chunk image

typedef short bf8   __attribute__((ext_vector_type(8)));
typedef float f32x4 __attribute__((ext_vector_type(4)));

__device__ __forceinline__ unsigned short f2bf(float f) {
    unsigned u = __float_as_uint(f);
    return (unsigned short)((u + 0x7FFFu + ((u >> 16) & 1u)) >> 16);   // RNE
}
__device__ __forceinline__ float bf2f(unsigned short h) {
    return __uint_as_float(((unsigned)h) << 16);
}

union PK { unsigned short u[8]; uint4 v; };

__global__ __launch_bounds__(512) void prep_kernel(const float* __restrict__ cb,
                                                   float* __restrict__ out,
                                                   float* __restrict__ cbn,
                                                   uint4* __restrict__ aplane,
                                                   int* __restrict__ counts_g,
                                                   float* __restrict__ loss_g)
{
    const int r = threadIdx.x;              // one code row per thread
    float v[64];
    float s = 0.f;
    #pragma unroll
    for (int i = 0; i < 64; ++i) {
        v[i] = cb[r * 64 + i];
        s = fmaf(v[i], v[i], s);
        out[OFF_CB + r * 64 + i] = v[i];    // raw codebook passthrough
    }
    const float inv = 1.0f / fmaxf(sqrtf(s), 1e-12f);
    const int c = r >> 6, cl = r & 63;      // chunk, local code
    #pragma unroll
    for (int kb = 0; kb < 8; ++kb) {
        PK ph, pm, pl;
        #pragma unroll
        for (int j = 0; j < 8; ++j) {
            float f = v[kb * 8 + j] * inv;
            cbn[r * 64 + kb * 8 + j] = f;
            ph.u[j] = f2bf(f);
            float r1 = f - bf2f(ph.u[j]);   // exact (Dekker split via RNE)
            pm.u[j] = f2bf(r1);
            float r2 = r1 - bf2f(pm.u[j]);  // exact
            pl.u[j] = f2bf(r2);
        }
        aplane[((size_t)(c * 3 + 0) * 8 + kb) * 66 + cl] = ph.v;
        aplane[((size_t)(c * 3 + 1) * 8 + kb) * 66 + cl] = pm.v;
        aplane[((size_t)(c * 3 + 2) * 8 + kb) * 66 + cl] = pl.v;
    }
    counts_g[r] = 0;
    if (r == 0) loss_g[0] = 0.f;
}

__global__ __launch_bounds__(256, 2) void main_kernel(const float* __restrict__ x,
                                                      const float* __restrict__ cbn,
                                                      const uint4* __restrict__ aplane,
                                                      int* __restrict__ counts_g,
                                                      float* __restrict__ loss_g,
                                                      float* __restrict__ out)
{
    __shared__ uint4 Albs[CHUNK_U4];        // [split][kb][66]  codes (64/chunk)
    __shared__ uint4 Blds[3][8][130];       // [split][kb][token] tokens
    __shared__ float inv_nx[BT];
    __shared__ int   idxs[BT];
    __shared__ int   counts_lds[NCODE];
    __shared__ float loss_lds;

    const int tid  = threadIdx.x;
    const int lane = tid & 63;
    const int wv   = tid >> 6;
    const int lx   = lane & 15;
    const int lg   = lane >> 4;
    const int tok0 = blockIdx.x * BT;

    counts_lds[tid] = 0; counts_lds[tid + 256] = 0;
    if (tid == 0) loss_lds = 0.f;

    // ---- stage tokens: split raw x (argmax is scale-invariant) into 3 bf16 planes ----
    {
        const int t = tid >> 1, h = tid & 1;
        const float4* xr = (const float4*)x + ((size_t)(tok0 + t) * 16 + h * 8);
        float ss = 0.f;
        #pragma unroll
        for (int q = 0; q < 4; ++q) {
            float4 a = xr[2 * q], b = xr[2 * q + 1];
            float f[8] = {a.x, a.y, a.z, a.w, b.x, b.y, b.z, b.w};
            PK ph, pm, pl;
            #pragma unroll
            for (int j = 0; j < 8; ++j) {
                ss = fmaf(f[j], f[j], ss);
                ph.u[j] = f2bf(f[j]);
                float r1 = f[j] - bf2f(ph.u[j]);
                pm.u[j] = f2bf(r1);
                float r2 = r1 - bf2f(pm.u[j]);
                pl.u[j] = f2bf(r2);
            }
            const int kb = 4 * h + q;
            Blds[0][kb][t] = ph.v;
            Blds[1][kb][t] = pm.v;
            Blds[2][kb][t] = pl.v;
        }
        ss += __shfl_xor(ss, 1);
        if (h == 0) inv_nx[t] = 1.0f / fmaxf(sqrtf(ss), 1e-12f);
    }

    // prefetch A chunk 0 into registers
    uint4 st[7];
    {
        const uint4* src = aplane;
        #pragma unroll
        for (int i = 0; i < 6; ++i) st[i] = src[tid + 256 * i];
        if (tid < 48) st[6] = src[tid + 1536];
    }
    __syncthreads();                        // B planes complete
    #pragma unroll
    for (int i = 0; i < 6; ++i) Albs[tid + 256 * i] = st[i];
    if (tid < 48) Albs[tid + 1536] = st[6];

    // token (B) fragments, held in registers for the whole kernel: [split][h][tt]
    const int wt = 32 * wv;
    bf8 bfr[3][2][2];
    #pragma unroll
    for (int s = 0; s < 3; ++s)
        #pragma unroll
        for (int h = 0; h < 2; ++h) {
            bfr[s][h][0] = *(const bf8*)&Blds[s][4 * h + lg][wt + lx];
            bfr[s][h][1] = *(const bf8*)&Blds[s][4 * h + lg][wt + 16 + lx];
        }
    __syncthreads();                        // Albs chunk 0 ready

    float bm0 = -3e38f, bm1 = -3e38f;
    int   bi0 = 0,      bi1 = 0;
    // pass order small→large: hl, lh, mm, hm, mh, hh  (split idx 0=hi 1=mid 2=lo)
    static const int SA[6] = {0, 2, 1, 0, 1, 0};
    static const int SB[6] = {2, 0, 1, 1, 0, 0};

    for (int cc = 0; cc < 8; ++cc) {
        if (cc < 7) {                       // async-stage next chunk into regs
            const uint4* src = aplane + (size_t)(cc + 1) * CHUNK_U4;
            #pragma unroll
            for (int i = 0; i < 6; ++i) st[i] = src[tid + 256 * i];
            if (tid < 48) st[6] = src[tid + 1536];
        }
        #pragma unroll
        for (int cp = 0; cp < 2; ++cp) {
            const int ct = 2 * cp;
            bf8 af[3][2][2];                // code (A) fragments [split][h][which]
            #pragma unroll
            for (int s = 0; s < 3; ++s)
                #pragma unroll
                for (int h = 0; h < 2; ++h) {
                    const uint4* base = &Albs[(s * 8 + 4 * h + lg) * 66];
                    af[s][h][0] = *(const bf8*)(base + ct * 16 + lx);
                    af[s][h][1] = *(const bf8*)(base + (ct + 1) * 16 + lx);
                }
            f32x4 a00 = {0.f, 0.f, 0.f, 0.f};
            f32x4 a01 = a00, a10 = a00, a11 = a00;
            #pragma unroll
            for (int p = 0; p < 6; ++p)
                #pragma unroll
                for (int h = 0; h < 2; ++h) {
                    a00 = __builtin_amdgcn_mfma_f32_16x16x32_bf16(af[SA[p]][h][0], bfr[SB[p]][h][0], a00, 0, 0, 0);
                    a01 = __builtin_amdgcn_mfma_f32_16x16x32_bf16(af[SA[p]][h][0], bfr[SB[p]][h][1], a01, 0, 0, 0);
                    a10 = __builtin_amdgcn_mfma_f32_16x16x32_bf16(af[SA[p]][h][1], bfr[SB[p]][h][0], a10, 0, 0, 0);
                    a11 = __builtin_amdgcn_mfma_f32_16x16x32_bf16(af[SA[p]][h][1], bfr[SB[p]][h][1], a11, 0, 0, 0);
                }
            // running argmax, strictly ascending code order (first-max tie rule)
            const int cb0 = cc * 64 + ct * 16 + lg * 4;
            #pragma unroll
            for (int j = 0; j < 4; ++j) {
                if (a00[j] > bm0) { bm0 = a00[j]; bi0 = cb0 + j; }
                if (a01[j] > bm1) { bm1 = a01[j]; bi1 = cb0 + j; }
            }
            #pragma unroll
            for (int j = 0; j < 4; ++j) {
                if (a10[j] > bm0) { bm0 = a10[j]; bi0 = cb0 + 16 + j; }
                if (a11[j] > bm1) { bm1 = a11[j]; bi1 = cb0 + 16 + j; }
            }
        }
        __syncthreads();                    // done reading Albs
        if (cc < 7) {
            #pragma unroll
            for (int i = 0; i < 6; ++i) Albs[tid + 256 * i] = st[i];
            if (tid < 48) Albs[tid + 1536] = st[6];
            __syncthreads();
        }
    }

    // combine lanes {l, l^16, l^32, l^48} (same token column), min-index ties
    #pragma unroll
    for (int off = 16; off < 64; off <<= 1) {
        float v0 = __shfl_xor(bm0, off); int i0 = __shfl_xor(bi0, off);
        float v1 = __shfl_xor(bm1, off); int i1 = __shfl_xor(bi1, off);
        if (v0 > bm0 || (v0 == bm0 && i0 < bi0)) { bm0 = v0; bi0 = i0; }
        if (v1 > bm1 || (v1 == bm1 && i1 < bi1)) { bm1 = v1; bi1 = i1; }
    }
    if (lg == 0) {
        const int t0 = wt + lx, t1 = wt + 16 + lx;
        idxs[t0] = bi0; idxs[t1] = bi1;
        atomicAdd(&counts_lds[bi0], 1);
        atomicAdd(&counts_lds[bi1], 1);
        // ||q - x_hat||^2 = 2 - 2*cos ; cos = (x . c_hat) * inv_nx
        float lp = (2.f - 2.f * bm0 * inv_nx[t0]) + (2.f - 2.f * bm1 * inv_nx[t1]);
        atomicAdd(&loss_lds, lp);
    }
    __syncthreads();

    if (tid < BT) out[OFF_IDX + tok0 + tid] = (float)idxs[tid];

    // quantized_st forward value = normalized-codebook gather
    for (int e = tid; e < BT * 64; e += 256) {
        const int t = e >> 6, d = e & 63;
        out[OFF_Q + (size_t)(tok0 + t) * 64 + d] = cbn[idxs[t] * 64 + d];
    }

    int c0 = counts_lds[tid], c1 = counts_lds[tid + 256];
    if (c0) atomicAdd(&counts_g[tid], c0);
    if (c1) atomicAdd(&counts_g[tid + 256], c1);
    if (tid == 0) atomicAdd(loss_g, loss_lds);
}

__global__ __launch_bounds__(512) void fin_kernel(const int* __restrict__ counts_g,
                                                  const float* __restrict__ loss_g,
                                                  float* __restrict__ out)
{
    __shared__ double red[512];
    int t = threadIdx.x;
    float p = (float)counts_g[t] * (1.0f / (float)T_TOK);
    red[t] = (double)(p * logf(p + 1e-10f));
    __syncthreads();
    for (int s = 256; s > 0; s >>= 1) {
        if (t < s) red[t] += red[t + s];
        __syncthreads();
    }
    if (t == 0) {
        out[OFF_PERP] = expf(-(float)red[0]);
        out[OFF_LOSS] = loss_g[0] * (1.25f / ((float)T_TOK * 64.f));
    }
}

extern "C" void kernel_launch(void* const* d_in, const int* in_sizes, int n_in,
                              void* d_out, int out_size, void* d_ws, size_t ws_size,
                              hipStream_t stream)
{
    const float* x  = (const float*)d_in[0];   // [128,8,128,64] fp32
    const float* cb = (const float*)d_in[1];   // [512,64] fp32
    float* out = (float*)d_out;
    char*  ws  = (char*)d_ws;
    float* loss_g   = (float*)(ws);
    int*   counts_g = (int*)(ws + 64);
    float* cbn      = (float*)(ws + CBN_OFF);
    uint4* aplane   = (uint4*)(ws + APLANE_OFF);

    prep_kernel<<<1, 512, 0, stream>>>(cb, out, cbn, aplane, counts_g, loss_g);
    main_kernel<<<T_TOK / BT, 256, 0, stream>>>(x, cbn, aplane, counts_g, loss_g, out);
    fin_kernel<<<1, 512, 0, stream>>>(counts_g, loss_g, out);
}

// Round 3
// 94.470 us; speedup vs baseline: 1.5025x; 1.1716x over previous
//
#include <hip/hip_runtime.h>
#include <math.h>

#define T_TOK 131072
#define NCODE 512

// output layout (float32, concatenated in return order)
#define OFF_LOSS 0
#define OFF_Q    1                    // 8388608 elements
#define OFF_PERP 8388609
#define OFF_CB   8388610              // 32768 elements
#define OFF_IDX  8421378              // 131072 elements

// ws layout (bytes):
//   0      : float loss_acc
//   64     : int counts[512]
//   4096   : float cbn[512*64]      normalized codebook fp32
//   135168 : uint4 apack[8cc][4ct][3s][2h][64 lanes]  split bf16 codebook,
//            pre-linearized in LDS-image order (24576 B per cc chunk)
#define CBN_OFF   4096
#define APACK_OFF 135168
#define CHUNK_B   24576

typedef short bf8   __attribute__((ext_vector_type(8)));
typedef float f32x4 __attribute__((ext_vector_type(4)));

typedef __attribute__((address_space(3))) unsigned int lds_u32;
typedef const __attribute__((address_space(1))) unsigned int glb_u32;

__device__ __forceinline__ unsigned short f2bf(float f) {
    unsigned u = __float_as_uint(f);
    return (unsigned short)((u + 0x7FFFu + ((u >> 16) & 1u)) >> 16);   // RNE
}
__device__ __forceinline__ float bf2f(unsigned short h) {
    return __uint_as_float(((unsigned)h) << 16);
}
union PK { unsigned short u[8]; uint4 v; };

// ---- prep: 8 blocks x 64 threads, one code per thread ----
__global__ __launch_bounds__(64) void prep_kernel(const float* __restrict__ cb,
                                                  float* __restrict__ out,
                                                  float* __restrict__ cbn,
                                                  uint4* __restrict__ apack,
                                                  int* __restrict__ counts_g,
                                                  float* __restrict__ loss_g)
{
    const int c = blockIdx.x * 64 + threadIdx.x;
    float v[64];
    float s = 0.f;
    const float4* src = (const float4*)(cb + c * 64);
    float4* rawdst = (float4*)(out + OFF_CB + c * 64);
    #pragma unroll
    for (int q = 0; q < 16; ++q) {
        float4 t = src[q];
        v[4*q] = t.x; v[4*q+1] = t.y; v[4*q+2] = t.z; v[4*q+3] = t.w;
        s = fmaf(t.x,t.x, fmaf(t.y,t.y, fmaf(t.z,t.z, fmaf(t.w,t.w, s))));
        rawdst[q] = t;                                  // raw passthrough
    }
    const float inv = 1.0f / fmaxf(sqrtf(s), 1e-12f);
    const int cc = c >> 6, ct = (c >> 4) & 3, cl = c & 15;
    const int base = (cc * 4 + ct) * 3;
    #pragma unroll
    for (int g = 0; g < 8; ++g) {                       // h = g>>2, lg = g&3
        PK ph, pm, pl;
        #pragma unroll
        for (int j = 0; j < 8; ++j) {
            float f = v[g * 8 + j] * inv;
            cbn[c * 64 + g * 8 + j] = f;
            ph.u[j] = f2bf(f);
            float r1 = f - bf2f(ph.u[j]);               // exact Dekker residual
            pm.u[j] = f2bf(r1);
            float r2 = r1 - bf2f(pm.u[j]);              // exact
            pl.u[j] = f2bf(r2);
        }
        const int h = g >> 2, lg = g & 3;
        apack[((base + 0) * 2 + h) * 64 + lg * 16 + cl] = ph.v;
        apack[((base + 1) * 2 + h) * 64 + lg * 16 + cl] = pm.v;
        apack[((base + 2) * 2 + h) * 64 + lg * 16 + cl] = pl.v;
    }
    counts_g[c] = 0;
    if (c == 0) loss_g[0] = 0.f;
}

// 8 MFMAs of one (A-split, B-split) pass over both ct tiles and both h k-blocks
#define PASS(A0, A1, B0, B1, sb)                                                        \
    a00 = __builtin_amdgcn_mfma_f32_16x16x32_bf16(A0, bfr[sb][0][0], a00, 0, 0, 0);     \
    a01 = __builtin_amdgcn_mfma_f32_16x16x32_bf16(A0, bfr[sb][0][1], a01, 0, 0, 0);     \
    a10 = __builtin_amdgcn_mfma_f32_16x16x32_bf16(B0, bfr[sb][0][0], a10, 0, 0, 0);     \
    a11 = __builtin_amdgcn_mfma_f32_16x16x32_bf16(B0, bfr[sb][0][1], a11, 0, 0, 0);     \
    a00 = __builtin_amdgcn_mfma_f32_16x16x32_bf16(A1, bfr[sb][1][0], a00, 0, 0, 0);     \
    a01 = __builtin_amdgcn_mfma_f32_16x16x32_bf16(A1, bfr[sb][1][1], a01, 0, 0, 0);     \
    a10 = __builtin_amdgcn_mfma_f32_16x16x32_bf16(B1, bfr[sb][1][0], a10, 0, 0, 0);     \
    a11 = __builtin_amdgcn_mfma_f32_16x16x32_bf16(B1, bfr[sb][1][1], a11, 0, 0, 0);

__global__ __launch_bounds__(256, 4) void main_kernel(const float* __restrict__ x,
                                                      const float* __restrict__ cbn,
                                                      const uint4* __restrict__ apack,
                                                      int* __restrict__ counts_g,
                                                      float* __restrict__ loss_g,
                                                      float* __restrict__ out)
{
    __shared__ __align__(16) char Albs[CHUNK_B];        // one A chunk: [ct][s][h][lane]*16B
    __shared__ int counts_lds[NCODE];

    const int tid  = threadIdx.x;
    const int lane = tid & 63;
    const int wv   = tid >> 6;
    const int lx   = lane & 15;
    const int lg   = lane >> 4;
    const int tok0 = blockIdx.x * 128;
    const int wt   = wv * 32;                           // this wave's first token

    counts_lds[tid] = 0; counts_lds[tid + 256] = 0;

    // ---- issue chunk-0 staging (wave wv covers 1KB segments wv*6 .. wv*6+5) ----
    {
        const char* gb = (const char*)apack;
        #pragma unroll
        for (int i = 0; i < 6; ++i) {
            const int seg = wv * 6 + i;
            __builtin_amdgcn_global_load_lds(
                (glb_u32*)(gb + seg * 1024 + lane * 16),
                (lds_u32*)(Albs + seg * 1024), 16, 0, 0);
        }
    }

    // ---- load + split own token fragments directly from global (no LDS) ----
    // lane owns tokens wt+lx and wt+16+lx, dims h*32 + lg*8 .. +8
    bf8 bfr[3][2][2];                                   // [split][h][tt]
    float inv_n[2];
    #pragma unroll
    for (int tt = 0; tt < 2; ++tt) {
        float ss = 0.f;
        const float* xr = x + (size_t)(tok0 + wt + tt * 16 + lx) * 64 + lg * 8;
        #pragma unroll
        for (int h = 0; h < 2; ++h) {
            float4 a = *(const float4*)(xr + h * 32);
            float4 b = *(const float4*)(xr + h * 32 + 4);
            float f[8] = {a.x, a.y, a.z, a.w, b.x, b.y, b.z, b.w};
            PK ph, pm, pl;
            #pragma unroll
            for (int j = 0; j < 8; ++j) {
                ss = fmaf(f[j], f[j], ss);
                ph.u[j] = f2bf(f[j]);
                float r1 = f[j] - bf2f(ph.u[j]);
                pm.u[j] = f2bf(r1);
                float r2 = r1 - bf2f(pm.u[j]);
                pl.u[j] = f2bf(r2);
            }
            bfr[0][h][tt] = *(bf8*)&ph;
            bfr[1][h][tt] = *(bf8*)&pm;
            bfr[2][h][tt] = *(bf8*)&pl;
        }
        // full |x|^2: reduce over the 4 lg-groups sharing this token column
        ss += __shfl_xor(ss, 16);
        ss += __shfl_xor(ss, 32);
        inv_n[tt] = 1.0f / fmaxf(sqrtf(ss), 1e-12f);
    }
    __syncthreads();                                    // chunk 0 in LDS; counts zeroed

    float bm0 = -3e38f, bm1 = -3e38f;
    int   bi0 = 0,      bi1 = 0;

    #pragma unroll 1
    for (int cc = 0; cc < 8; ++cc) {
        #pragma unroll
        for (int cp = 0; cp < 2; ++cp) {
            const int ct0 = 2 * cp;
            f32x4 a00 = {0.f, 0.f, 0.f, 0.f};
            f32x4 a01 = a00, a10 = a00, a11 = a00;

            // fragment read: LDS byte offset ((ct*3+s)*2+h)*1024 + lane*16
            #define RDAF(ct, s, h) (*(const bf8*)(Albs + (((ct) * 3 + (s)) * 2 + (h)) * 1024 + lane * 16))

            // pass order small->large: lh, mm, mh, hl, hm, hh (A-split-grouped)
            bf8 A0 = RDAF(ct0, 2, 0), A1 = RDAF(ct0, 2, 1);
            bf8 B0 = RDAF(ct0 + 1, 2, 0), B1 = RDAF(ct0 + 1, 2, 1);
            PASS(A0, A1, B0, B1, 0)                     // lh
            A0 = RDAF(ct0, 1, 0); A1 = RDAF(ct0, 1, 1);
            B0 = RDAF(ct0 + 1, 1, 0); B1 = RDAF(ct0 + 1, 1, 1);
            PASS(A0, A1, B0, B1, 1)                     // mm
            PASS(A0, A1, B0, B1, 0)                     // mh
            A0 = RDAF(ct0, 0, 0); A1 = RDAF(ct0, 0, 1);
            B0 = RDAF(ct0 + 1, 0, 0); B1 = RDAF(ct0 + 1, 0, 1);
            PASS(A0, A1, B0, B1, 2)                     // hl
            PASS(A0, A1, B0, B1, 1)                     // hm
            PASS(A0, A1, B0, B1, 0)                     // hh

            // running argmax, strictly ascending code order (first-max tie rule)
            const int cb0 = cc * 64 + ct0 * 16 + lg * 4;
            #pragma unroll
            for (int j = 0; j < 4; ++j) {
                if (a00[j] > bm0) { bm0 = a00[j]; bi0 = cb0 + j; }
                if (a01[j] > bm1) { bm1 = a01[j]; bi1 = cb0 + j; }
            }
            #pragma unroll
            for (int j = 0; j < 4; ++j) {
                if (a10[j] > bm0) { bm0 = a10[j]; bi0 = cb0 + 16 + j; }
                if (a11[j] > bm1) { bm1 = a11[j]; bi1 = cb0 + 16 + j; }
            }
        }
        __syncthreads();                                // all waves done reading Albs
        if (cc < 7) {                                   // single-buffer re-stage; TLP hides drain
            const char* gb = (const char*)apack + (size_t)(cc + 1) * CHUNK_B;
            #pragma unroll
            for (int i = 0; i < 6; ++i) {
                const int seg = wv * 6 + i;
                __builtin_amdgcn_global_load_lds(
                    (glb_u32*)(gb + seg * 1024 + lane * 16),
                    (lds_u32*)(Albs + seg * 1024), 16, 0, 0);
            }
            __syncthreads();                            // vmcnt(0) drain -> chunk ready
        }
    }

    // ---- combine lanes {l, l^16, l^32, l^48} (same token column), min-index ties ----
    #pragma unroll
    for (int off = 16; off < 64; off <<= 1) {
        float v0 = __shfl_xor(bm0, off); int i0 = __shfl_xor(bi0, off);
        float v1 = __shfl_xor(bm1, off); int i1 = __shfl_xor(bi1, off);
        if (v0 > bm0 || (v0 == bm0 && i0 < bi0)) { bm0 = v0; bi0 = i0; }
        if (v1 > bm1 || (v1 == bm1 && i1 < bi1)) { bm1 = v1; bi1 = i1; }
    }

    if (lg == 0) {                                      // lanes 0-15: one per token column
        atomicAdd(&counts_lds[bi0], 1);
        atomicAdd(&counts_lds[bi1], 1);
        out[OFF_IDX + tok0 + wt + lx]      = (float)bi0;
        out[OFF_IDX + tok0 + wt + 16 + lx] = (float)bi1;
        // ||q - x_hat||^2 = 2 - 2*cos ; cos = (x . c_hat) * inv|x|
        float lp = (2.f - 2.f * bm0 * inv_n[0]) + (2.f - 2.f * bm1 * inv_n[1]);
        lp += __shfl_xor(lp, 1); lp += __shfl_xor(lp, 2);
        lp += __shfl_xor(lp, 4); lp += __shfl_xor(lp, 8);
        if (lx == 0) atomicAdd(loss_g, lp);
    }

    // ---- quantized_st rows: idx broadcast by shfl, row gather from L2-resident cbn ----
    #pragma unroll 4
    for (int i = 0; i < 32; ++i) {
        int idx = __shfl((i < 16) ? bi0 : bi1, i & 15);
        float vq = cbn[idx * 64 + lane];
        out[OFF_Q + (size_t)(tok0 + wt + i) * 64 + lane] = vq;
    }

    __syncthreads();                                    // all histogram atomics done
    int c0 = counts_lds[tid], c1 = counts_lds[tid + 256];
    if (c0) atomicAdd(&counts_g[tid], c0);
    if (c1) atomicAdd(&counts_g[tid + 256], c1);
}

__global__ __launch_bounds__(512) void fin_kernel(const int* __restrict__ counts_g,
                                                  const float* __restrict__ loss_g,
                                                  float* __restrict__ out)
{
    __shared__ double red[512];
    int t = threadIdx.x;
    float p = (float)counts_g[t] * (1.0f / (float)T_TOK);
    red[t] = (double)(p * logf(p + 1e-10f));
    __syncthreads();
    for (int s = 256; s > 0; s >>= 1) {
        if (t < s) red[t] += red[t + s];
        __syncthreads();
    }
    if (t == 0) {
        out[OFF_PERP] = expf(-(float)red[0]);
        out[OFF_LOSS] = loss_g[0] * (1.25f / ((float)T_TOK * 64.f));
    }
}

extern "C" void kernel_launch(void* const* d_in, const int* in_sizes, int n_in,
                              void* d_out, int out_size, void* d_ws, size_t ws_size,
                              hipStream_t stream)
{
    const float* x  = (const float*)d_in[0];   // [128,8,128,64] fp32
    const float* cb = (const float*)d_in[1];   // [512,64] fp32
    float* out = (float*)d_out;
    char*  ws  = (char*)d_ws;
    float* loss_g   = (float*)(ws);
    int*   counts_g = (int*)(ws + 64);
    float* cbn      = (float*)(ws + CBN_OFF);
    uint4* apack    = (uint4*)(ws + APACK_OFF);

    prep_kernel<<<8, 64, 0, stream>>>(cb, out, cbn, apack, counts_g, loss_g);
    main_kernel<<<T_TOK / 128, 256, 0, stream>>>(x, cbn, apack, counts_g, loss_g, out);
    fin_kernel<<<1, 512, 0, stream>>>(counts_g, loss_g, out);
}

// Round 4
// 80.031 us; speedup vs baseline: 1.7735x; 1.1804x over previous
//
#include <hip/hip_runtime.h>
#include <math.h>

#define T_TOK 131072
#define NCODE 512

// output layout (float32, concatenated in return order)
#define OFF_LOSS 0
#define OFF_Q    1                    // 8388608 elements
#define OFF_PERP 8388609
#define OFF_CB   8388610              // 32768 elements
#define OFF_IDX  8421378              // 131072 elements

// ws layout (bytes):
//   0      : float loss_acc
//   64     : int counts[512]
//   4096   : float cbn[512*64]      normalized codebook fp32
//   135168 : uint4 apack[8cc][4ct][3s][2h][64 lanes]  split bf16 codebook,
//            pre-linearized in LDS-image order (24576 B per cc chunk)
#define CBN_OFF   4096
#define APACK_OFF 135168
#define CHUNK_B   24576

typedef short bf8   __attribute__((ext_vector_type(8)));
typedef float f32x4 __attribute__((ext_vector_type(4)));

typedef __attribute__((address_space(3))) unsigned int lds_u32;
typedef const __attribute__((address_space(1))) unsigned int glb_u32;

__device__ __forceinline__ unsigned short f2bf(float f) {
    unsigned u = __float_as_uint(f);
    return (unsigned short)((u + 0x7FFFu + ((u >> 16) & 1u)) >> 16);   // RNE
}
__device__ __forceinline__ float bf2f(unsigned short h) {
    return __uint_as_float(((unsigned)h) << 16);
}
union PK { unsigned short u[8]; uint4 v; };

// ---- prep: 8 blocks x 64 threads, one code per thread ----
__global__ __launch_bounds__(64) void prep_kernel(const float* __restrict__ cb,
                                                  float* __restrict__ out,
                                                  float* __restrict__ cbn,
                                                  uint4* __restrict__ apack,
                                                  int* __restrict__ counts_g,
                                                  float* __restrict__ loss_g)
{
    const int c = blockIdx.x * 64 + threadIdx.x;
    float v[64];
    float s = 0.f;
    const float4* src = (const float4*)(cb + c * 64);
    float4* rawdst = (float4*)(out + OFF_CB + c * 64);
    #pragma unroll
    for (int q = 0; q < 16; ++q) {
        float4 t = src[q];
        v[4*q] = t.x; v[4*q+1] = t.y; v[4*q+2] = t.z; v[4*q+3] = t.w;
        s = fmaf(t.x,t.x, fmaf(t.y,t.y, fmaf(t.z,t.z, fmaf(t.w,t.w, s))));
        rawdst[q] = t;                                  // raw passthrough
    }
    const float inv = 1.0f / fmaxf(sqrtf(s), 1e-12f);
    const int cc = c >> 6, ct = (c >> 4) & 3, cl = c & 15;
    const int base = (cc * 4 + ct) * 3;
    #pragma unroll
    for (int g = 0; g < 8; ++g) {                       // h = g>>2, lg = g&3
        PK ph, pm, pl;
        #pragma unroll
        for (int j = 0; j < 8; ++j) {
            float f = v[g * 8 + j] * inv;
            cbn[c * 64 + g * 8 + j] = f;
            ph.u[j] = f2bf(f);
            float r1 = f - bf2f(ph.u[j]);               // exact Dekker residual
            pm.u[j] = f2bf(r1);
            float r2 = r1 - bf2f(pm.u[j]);              // exact
            pl.u[j] = f2bf(r2);
        }
        const int h = g >> 2, lg = g & 3;
        apack[((base + 0) * 2 + h) * 64 + lg * 16 + cl] = ph.v;
        apack[((base + 1) * 2 + h) * 64 + lg * 16 + cl] = pm.v;
        apack[((base + 2) * 2 + h) * 64 + lg * 16 + cl] = pl.v;
    }
    counts_g[c] = 0;
    if (c == 0) loss_g[0] = 0.f;
}

// one (A-split, B-split) pass: 2 A tiles x 2 h k-blocks x 4 token frags = 16 MFMA
#define PASS(sb)                                                                         \
    {                                                                                    \
        _Pragma("unroll")                                                                \
        for (int tt = 0; tt < 4; ++tt) {                                                 \
            acc0[tt] = __builtin_amdgcn_mfma_f32_16x16x32_bf16(A00, bfr[sb][0][tt], acc0[tt], 0, 0, 0); \
            acc1[tt] = __builtin_amdgcn_mfma_f32_16x16x32_bf16(A10, bfr[sb][0][tt], acc1[tt], 0, 0, 0); \
            acc0[tt] = __builtin_amdgcn_mfma_f32_16x16x32_bf16(A01, bfr[sb][1][tt], acc0[tt], 0, 0, 0); \
            acc1[tt] = __builtin_amdgcn_mfma_f32_16x16x32_bf16(A11, bfr[sb][1][tt], acc1[tt], 0, 0, 0); \
        }                                                                                \
    }

// fragment read: LDS byte offset ((ct*3+s)*2+h)*1024 + lane*16
#define RDAF(buf, ct, s, h) (*(const bf8*)((buf) + (((ct) * 3 + (s)) * 2 + (h)) * 1024 + lane * 16))

// wave wv stages segments wv*3 .. wv*3+2 of one 24KB chunk image
#define STAGE(dst, src)                                                                  \
    {                                                                                    \
        _Pragma("unroll")                                                                \
        for (int i_ = 0; i_ < 3; ++i_) {                                                 \
            const int seg_ = wv * 3 + i_;                                                \
            __builtin_amdgcn_global_load_lds((glb_u32*)((src) + seg_ * 1024 + lane * 16),\
                                             (lds_u32*)((dst) + seg_ * 1024), 16, 0, 0); \
        }                                                                                \
    }

__global__ __launch_bounds__(512, 2) void main_kernel(const float* __restrict__ x,
                                                      const float* __restrict__ cbn,
                                                      const uint4* __restrict__ apack,
                                                      int* __restrict__ counts_g,
                                                      float* __restrict__ loss_g,
                                                      float* __restrict__ out)
{
    __shared__ __align__(16) char Albs[2][CHUNK_B];     // double-buffered A chunk
    __shared__ int counts_lds[NCODE];

    const int tid  = threadIdx.x;
    const int lane = tid & 63;
    const int wv   = tid >> 6;                          // 0..7
    const int lx   = lane & 15;
    const int lg   = lane >> 4;
    const int tok0 = blockIdx.x * 512;
    const int wt   = wv * 64;                           // this wave's first token

    counts_lds[tid] = 0;

    // ---- issue chunk-0 staging into buffer 0 (latency hides under token split) ----
    {
        const char* gb = (const char*)apack;
        STAGE(&Albs[0][0], gb)
    }

    // ---- load + split own token fragments directly from global (no LDS for B) ----
    // lane owns tokens wt + tt*16 + lx (tt=0..3), dims lg*8..+8 and 32+lg*8..+8
    bf8 bfr[3][2][4];                                   // [split][h][tt]
    float inv_n[4];
    #pragma unroll
    for (int tt = 0; tt < 4; ++tt) {
        float ss = 0.f;
        const float* xr = x + (size_t)(tok0 + wt + tt * 16 + lx) * 64 + lg * 8;
        #pragma unroll
        for (int h = 0; h < 2; ++h) {
            float4 a = *(const float4*)(xr + h * 32);
            float4 b = *(const float4*)(xr + h * 32 + 4);
            float f[8] = {a.x, a.y, a.z, a.w, b.x, b.y, b.z, b.w};
            PK ph, pm, pl;
            #pragma unroll
            for (int j = 0; j < 8; ++j) {
                ss = fmaf(f[j], f[j], ss);
                ph.u[j] = f2bf(f[j]);
                float r1 = f[j] - bf2f(ph.u[j]);
                pm.u[j] = f2bf(r1);
                float r2 = r1 - bf2f(pm.u[j]);
                pl.u[j] = f2bf(r2);
            }
            bfr[0][h][tt] = *(bf8*)&ph;
            bfr[1][h][tt] = *(bf8*)&pm;
            bfr[2][h][tt] = *(bf8*)&pl;
        }
        // full |x|^2: reduce over the 4 lg-groups sharing this token column
        ss += __shfl_xor(ss, 16);
        ss += __shfl_xor(ss, 32);
        inv_n[tt] = 1.0f / fmaxf(sqrtf(ss), 1e-12f);
    }
    __syncthreads();                                    // chunk 0 resident; counts zeroed

    float bm[4] = {-3e38f, -3e38f, -3e38f, -3e38f};
    int   bi[4] = {0, 0, 0, 0};

    #pragma unroll 2
    for (int cc = 0; cc < 8; ++cc) {
        const char* bufc = &Albs[cc & 1][0];
        char*       bufn = &Albs[(cc & 1) ^ 1][0];

        if (cc < 7) {                                   // prefetch next chunk first
            const char* gb = (const char*)apack + (size_t)(cc + 1) * CHUNK_B;
            STAGE(bufn, gb)
        }

        #pragma unroll
        for (int cp = 0; cp < 2; ++cp) {
            const int ct0 = 2 * cp;
            f32x4 zero = {0.f, 0.f, 0.f, 0.f};
            f32x4 acc0[4] = {zero, zero, zero, zero};
            f32x4 acc1[4] = {zero, zero, zero, zero};

            // pass order small->large: lh, mm, mh, hl, hm, hh (A-split-grouped)
            bf8 A00 = RDAF(bufc, ct0, 2, 0), A01 = RDAF(bufc, ct0, 2, 1);
            bf8 A10 = RDAF(bufc, ct0 + 1, 2, 0), A11 = RDAF(bufc, ct0 + 1, 2, 1);
            PASS(0)                                     // lh
            A00 = RDAF(bufc, ct0, 1, 0); A01 = RDAF(bufc, ct0, 1, 1);
            A10 = RDAF(bufc, ct0 + 1, 1, 0); A11 = RDAF(bufc, ct0 + 1, 1, 1);
            PASS(1)                                     // mm
            PASS(0)                                     // mh
            A00 = RDAF(bufc, ct0, 0, 0); A01 = RDAF(bufc, ct0, 0, 1);
            A10 = RDAF(bufc, ct0 + 1, 0, 0); A11 = RDAF(bufc, ct0 + 1, 0, 1);
            PASS(2)                                     // hl
            PASS(1)                                     // hm
            PASS(0)                                     // hh

            // running argmax, strictly ascending code order (first-max tie rule)
            const int cb0 = cc * 64 + ct0 * 16 + lg * 4;
            #pragma unroll
            for (int tt = 0; tt < 4; ++tt)
                #pragma unroll
                for (int j = 0; j < 4; ++j)
                    if (acc0[tt][j] > bm[tt]) { bm[tt] = acc0[tt][j]; bi[tt] = cb0 + j; }
            #pragma unroll
            for (int tt = 0; tt < 4; ++tt)
                #pragma unroll
                for (int j = 0; j < 4; ++j)
                    if (acc1[tt][j] > bm[tt]) { bm[tt] = acc1[tt][j]; bi[tt] = cb0 + 16 + j; }
        }
        __syncthreads();      // all waves done reading bufc; next-chunk stage drained
    }

    // ---- combine lanes {l, l^16, l^32, l^48} (same token column), min-index ties ----
    #pragma unroll
    for (int tt = 0; tt < 4; ++tt) {
        #pragma unroll
        for (int off = 16; off < 64; off <<= 1) {
            float v2 = __shfl_xor(bm[tt], off);
            int   i2 = __shfl_xor(bi[tt], off);
            if (v2 > bm[tt] || (v2 == bm[tt] && i2 < bi[tt])) { bm[tt] = v2; bi[tt] = i2; }
        }
    }

    if (lg == 0) {                                      // lanes 0-15: one per token column
        float lp = 0.f;
        #pragma unroll
        for (int tt = 0; tt < 4; ++tt) {
            atomicAdd(&counts_lds[bi[tt]], 1);
            out[OFF_IDX + tok0 + wt + tt * 16 + lx] = (float)bi[tt];
            // ||q - x_hat||^2 = 2 - 2*cos ; cos = (x . c_hat) * inv|x|
            lp += 2.f - 2.f * bm[tt] * inv_n[tt];
        }
        lp += __shfl_xor(lp, 1); lp += __shfl_xor(lp, 2);
        lp += __shfl_xor(lp, 4); lp += __shfl_xor(lp, 8);
        if (lx == 0) atomicAdd(loss_g, lp);
    }

    // ---- quantized_st rows: idx broadcast by shfl, row gather from L2-resident cbn ----
    #pragma unroll
    for (int tt = 0; tt < 4; ++tt) {
        const int b = bi[tt];
        #pragma unroll 4
        for (int i = 0; i < 16; ++i) {
            int idx = __shfl(b, i);
            out[OFF_Q + (size_t)(tok0 + wt + tt * 16 + i) * 64 + lane] = cbn[idx * 64 + lane];
        }
    }

    __syncthreads();                                    // all histogram atomics done
    int c0 = counts_lds[tid];
    if (c0) atomicAdd(&counts_g[tid], c0);
}

__global__ __launch_bounds__(512) void fin_kernel(const int* __restrict__ counts_g,
                                                  const float* __restrict__ loss_g,
                                                  float* __restrict__ out)
{
    __shared__ double red[512];
    int t = threadIdx.x;
    float p = (float)counts_g[t] * (1.0f / (float)T_TOK);
    red[t] = (double)(p * logf(p + 1e-10f));
    __syncthreads();
    for (int s = 256; s > 0; s >>= 1) {
        if (t < s) red[t] += red[t + s];
        __syncthreads();
    }
    if (t == 0) {
        out[OFF_PERP] = expf(-(float)red[0]);
        out[OFF_LOSS] = loss_g[0] * (1.25f / ((float)T_TOK * 64.f));
    }
}

extern "C" void kernel_launch(void* const* d_in, const int* in_sizes, int n_in,
                              void* d_out, int out_size, void* d_ws, size_t ws_size,
                              hipStream_t stream)
{
    const float* x  = (const float*)d_in[0];   // [128,8,128,64] fp32
    const float* cb = (const float*)d_in[1];   // [512,64] fp32
    float* out = (float*)d_out;
    char*  ws  = (char*)d_ws;
    float* loss_g   = (float*)(ws);
    int*   counts_g = (int*)(ws + 64);
    float* cbn      = (float*)(ws + CBN_OFF);
    uint4* apack    = (uint4*)(ws + APACK_OFF);

    prep_kernel<<<8, 64, 0, stream>>>(cb, out, cbn, apack, counts_g, loss_g);
    main_kernel<<<T_TOK / 512, 512, 0, stream>>>(x, cbn, apack, counts_g, loss_g, out);
    fin_kernel<<<1, 512, 0, stream>>>(counts_g, loss_g, out);
}